// Round 6
// baseline (172.737 us; speedup 1.0000x reference)
//
#include <hip/hip_runtime.h>
#include <math.h>

// Problem constants (B=8, T=1024, D=512, LEFT=16, RIGHT=0)
constexpr int Tn = 1024;
constexpr int Dn = 512;
constexpr int BT = 8192;
constexpr int WIN = 16;

typedef short bs8 __attribute__((ext_vector_type(8)));     // 8 bf16 (bit pattern)
typedef unsigned short us8 __attribute__((ext_vector_type(8)));
typedef float fx4 __attribute__((ext_vector_type(4)));

// bf16 helpers (self-contained, RNE)
__device__ inline unsigned short f2bf(float f) {
    unsigned int u = __float_as_uint(f);
    u += 0x7FFFu + ((u >> 16) & 1u);
    return (unsigned short)(u >> 16);
}
__device__ inline float bf2f(unsigned short h) {
    return __uint_as_float(((unsigned int)h) << 16);
}
// 2-bit chunk swizzle for B rows (spreads ds_read banks to ~2-way = free)
__device__ inline int fsw2(int n) { return (n & 3) ^ ((n >> 2) & 3); }

// ---------------------------------------------------------------------------
// Kernel 1 (wprep): blocks [0,256): split-K partials of G = M @ C^T
//                   blocks [256,320): split+transpose V (hi) -> Bt rows [512,1024)
// ---------------------------------------------------------------------------
__global__ __launch_bounds__(256) void wprep(
    const float* __restrict__ Mw, const float* __restrict__ Cw,
    const float* __restrict__ Vw,
    float* __restrict__ Gp, short* __restrict__ Bt)
{
    __shared__ float smem[64 * 65];
    const int blk = blockIdx.x;
    const int tid = threadIdx.x;

    if (blk < 256) {
        // ---- g_partial: Gp[kc][b][a] = sum_{j in 128-chunk} M[a,j] C[b,j] ----
        float* As = smem;              // [64][17]
        float* Bs = smem + 64 * 17;
        const int kch = blk >> 6;
        const int r6 = blk & 63;
        const int b0 = (r6 & 7) * 64;
        const int a0 = (r6 >> 3) * 64;
        const int tx = tid & 15, ty = tid >> 4;

        float acc[4][4] = {};
        for (int j0 = kch * 128; j0 < kch * 128 + 128; j0 += 16) {
            const int r = tid >> 2;
            const int c = (tid & 3) * 4;
            const float4 a = *(const float4*)(Mw + (size_t)(a0 + r) * Dn + j0 + c);
            As[r * 17 + c + 0] = a.x; As[r * 17 + c + 1] = a.y;
            As[r * 17 + c + 2] = a.z; As[r * 17 + c + 3] = a.w;
            const float4 b = *(const float4*)(Cw + (size_t)(b0 + r) * Dn + j0 + c);
            Bs[r * 17 + c + 0] = b.x; Bs[r * 17 + c + 1] = b.y;
            Bs[r * 17 + c + 2] = b.z; Bs[r * 17 + c + 3] = b.w;
            __syncthreads();
            #pragma unroll
            for (int kk = 0; kk < 16; ++kk) {
                float av[4], bv[4];
                #pragma unroll
                for (int i = 0; i < 4; ++i) av[i] = As[(ty * 4 + i) * 17 + kk];
                #pragma unroll
                for (int j = 0; j < 4; ++j) bv[j] = Bs[(tx * 4 + j) * 17 + kk];
                #pragma unroll
                for (int i = 0; i < 4; ++i)
                    #pragma unroll
                    for (int j = 0; j < 4; ++j)
                        acc[i][j] += av[i] * bv[j];
            }
            __syncthreads();
        }
        #pragma unroll
        for (int j = 0; j < 4; ++j) {
            const int b = b0 + tx * 4 + j;
            float4 col = make_float4(acc[0][j], acc[1][j], acc[2][j], acc[3][j]);
            *(float4*)(Gp + ((size_t)kch * 512 + b) * 512 + a0 + ty * 4) = col;
        }
    } else {
        // ---- split_v: Bt[512+n][k] = hi(V[k][n]) ----
        float* tile = smem;            // [64][65]
        const int z = blk - 256;
        const int k0 = (z & 7) * 64;
        const int n0 = (z >> 3) * 64;
        #pragma unroll
        for (int rr = 0; rr < 4; ++rr) {
            const int row = (tid >> 4) * 4 + rr;
            const int col = (tid & 15) * 4;
            const float4 w = *(const float4*)(Vw + (size_t)(k0 + row) * Dn + n0 + col);
            tile[row * 65 + col + 0] = w.x; tile[row * 65 + col + 1] = w.y;
            tile[row * 65 + col + 2] = w.z; tile[row * 65 + col + 3] = w.w;
        }
        __syncthreads();
        const int n  = tid >> 2;
        const int ks = (tid & 3) * 16;
        union { bs8 v; unsigned short u[8]; } hi0, hi1;
        #pragma unroll
        for (int i = 0; i < 8; ++i) {
            hi0.u[i] = f2bf(tile[(ks + i) * 65 + n]);
            hi1.u[i] = f2bf(tile[(ks + 8 + i) * 65 + n]);
        }
        short* base = Bt + (size_t)(512 + n0 + n) * 1024 + k0 + ks;
        *(bs8*)base       = hi0.v;
        *(bs8*)(base + 8) = hi1.v;
    }
}

// ---------------------------------------------------------------------------
// Kernel 2: pack G = sum of 4 partials, split hi/lo into Bt rows [0,512):
// Bt[b][a] = hi(G[a][b]), Bt[b][512+a] = lo.
// ---------------------------------------------------------------------------
__global__ __launch_bounds__(256) void pack_g(const float* __restrict__ Gp,
                                              short* __restrict__ Bt)
{
    const int i = blockIdx.x * 256 + threadIdx.x;   // 32768 threads
    const int b = i >> 6;
    const int a8 = (i & 63) * 8;
    float s[8] = {};
    #pragma unroll
    for (int kc = 0; kc < 4; ++kc) {
        const float* p = Gp + ((size_t)kc * 512 + b) * 512 + a8;
        const float4 p0 = *(const float4*)p;
        const float4 p1 = *(const float4*)(p + 4);
        s[0] += p0.x; s[1] += p0.y; s[2] += p0.z; s[3] += p0.w;
        s[4] += p1.x; s[5] += p1.y; s[6] += p1.z; s[7] += p1.w;
    }
    union { bs8 v; unsigned short u[8]; } hi, lo;
    #pragma unroll
    for (int j = 0; j < 8; ++j) {
        const unsigned short h = f2bf(s[j]);
        hi.u[j] = h;
        lo.u[j] = f2bf(s[j] - bf2f(h));
    }
    short* base = Bt + (size_t)b * 1024 + a8;
    *(bs8*)base         = hi.v;
    *(bs8*)(base + 512) = lo.v;
}

// ---------------------------------------------------------------------------
// Kernel 3 (fused): per block = 32 output tokens (one batch-aligned strip).
//   phase 0: stage X rows [t0-16, t0+32) -> LDS bf16 hi(48 rows)/lo(32 out rows)
//   phase 1: V' = Xhi @ Vhi (48 rows, K=512) -> per-block global scratch (bf16)
//   phase 2: Y = X @ G (32 rows, K'=1536: AhiGhi+AloGhi+AhiGlo) -> acc -> LDS
//   phase 3: per wave (8 tokens each): logits = Y . X (X = hi+lo exact to
//            2^-17; halo rows from f32 global), softmax, answer from V',
//            concat X-copy from hi+lo. Writes out rows.
// Invalid slots (src<0): logit = 0 exactly (exp(0) in denominator), no V term.
// LDS 144KB: [Ahi 48K | Alo 32K | Bdbuf 64K]; Y-f32 (64K) overlays Bdbuf.
// ---------------------------------------------------------------------------
__global__ __launch_bounds__(256, 1) void fused(
    const float* __restrict__ X, const short* __restrict__ Bt,
    unsigned short* __restrict__ Vblk, float* __restrict__ out)
{
    __shared__ __align__(16) short lds_s[73728];    // 144 KB
    short* Ahi = lds_s;                  // [48][512] chunk-swizzled by (r&7)
    short* Alo = lds_s + 48 * 512;       // [32][512] (output rows only)
    short* Bb0 = lds_s + 80 * 512;       // [512][32] chunk-swizzled by fsw2
    short* Bb1 = Bb0 + 512 * 32;
    float* YL  = (float*)Bb0;            // [32][512] f32, overlays B after GEMMs

    const int blk = blockIdx.x;          // 0..255
    const int r0  = blk * 32;
    const int bat = r0 >> 10;
    const int tt0 = r0 & 1023;
    const int tid = threadIdx.x;
    const int ln  = tid & 63;
    const int wid = tid >> 6;
    const int lrow = ln & 15;
    const int lkb  = ln >> 4;            // 0..3

    // ---- phase 0: stage A (X -> bf16 hi/lo, swizzled chunks) ----
    #pragma unroll
    for (int it = 0; it < 12; ++it) {
        const int idx = it * 256 + tid;  // 0..3071
        const int r = idx >> 6;          // LDS row 0..47
        const int j = idx & 63;          // 8-elem chunk within row
        const int tt = tt0 - 16 + r;
        const int tg = (tt < 0) ? (r0 - tt0) : (r0 - 16 + r);  // clamp (unused rows)
        const float4* xp = (const float4*)(X + (size_t)tg * 512 + j * 8);
        const float4 v0 = xp[0], v1 = xp[1];
        const float xs[8] = {v0.x, v0.y, v0.z, v0.w, v1.x, v1.y, v1.z, v1.w};
        union { bs8 v; unsigned short u[8]; } hi, lo;
        #pragma unroll
        for (int e = 0; e < 8; ++e) {
            const unsigned short h = f2bf(xs[e]);
            hi.u[e] = h;
            lo.u[e] = f2bf(xs[e] - bf2f(h));
        }
        const int js = j ^ (r & 7);
        *(bs8*)(Ahi + r * 512 + js * 8) = hi.v;
        if (r >= 16) *(bs8*)(Alo + (r - 16) * 512 + js * 8) = lo.v;
    }

    // ---- B staging: 512 rows x 32 k per step, linear LDS dest,
    //      pre-swizzled global source (rule: both-sides-or-neither) ----
    auto stageB = [&](short* dst, int nbase, int kb0) {
        #pragma unroll
        for (int q = 0; q < 8; ++q) {
            const int cc = q * 256 + tid;
            const int nr = cc >> 2;
            const int jj = cc & 3;
            const int js = jj ^ fsw2(nr);
            __builtin_amdgcn_global_load_lds(
                (const __attribute__((address_space(1))) unsigned int*)
                    (Bt + (size_t)(nbase + nr) * 1024 + kb0 + js * 8),
                (__attribute__((address_space(3))) unsigned int*)(dst + cc * 8),
                16, 0, 0);
        }
    };

    // ---- phase 1: V' GEMM (rows 0..47 hi, K=512) ----
    fx4 vacc[3][8] = {};
    auto computeV = [&](const short* bb, int k0) {
        bs8 a[3], b[8];
        #pragma unroll
        for (int mf = 0; mf < 3; ++mf) {
            const int i = mf * 16 + lrow;
            const int j = (k0 >> 3) + lkb;
            a[mf] = *(const bs8*)(Ahi + i * 512 + (j ^ (i & 7)) * 8);
        }
        #pragma unroll
        for (int nf = 0; nf < 8; ++nf) {
            const int nr = wid * 128 + nf * 16 + lrow;
            b[nf] = *(const bs8*)(bb + nr * 32 + (lkb ^ fsw2(nr)) * 8);
        }
        #pragma unroll
        for (int mf = 0; mf < 3; ++mf)
            #pragma unroll
            for (int nf = 0; nf < 8; ++nf)
                vacc[mf][nf] = __builtin_amdgcn_mfma_f32_16x16x32_bf16(
                    a[mf], b[nf], vacc[mf][nf], 0, 0, 0);
    };

    stageB(Bb0, 512, 0);
    __syncthreads();
    for (int k0 = 0; k0 < 512; k0 += 64) {
        stageB(Bb1, 512, k0 + 32);
        computeV(Bb0, k0);
        __syncthreads();
        if (k0 + 64 < 512) stageB(Bb0, 512, k0 + 64);
        computeV(Bb1, k0 + 32);
        __syncthreads();
    }
    // V' epilogue -> per-block scratch (local halo incl.), bf16
    #pragma unroll
    for (int mf = 0; mf < 3; ++mf)
        #pragma unroll
        for (int nf = 0; nf < 8; ++nf)
            #pragma unroll
            for (int r = 0; r < 4; ++r) {
                const int row = mf * 16 + lkb * 4 + r;
                const int col = wid * 128 + nf * 16 + lrow;
                Vblk[((size_t)blk * 48 + row) * 512 + col] = f2bf(vacc[mf][nf][r]);
            }
    __threadfence();   // make V' visible to other waves (read after barrier)

    // ---- phase 2: Y GEMM (out rows, K'=1536 = AhiGhi + AloGhi + AhiGlo) ----
    fx4 yacc[2][8] = {};
    auto computeY = [&](const short* bb, int k0) {
        const short* ap; int koff;
        if (k0 < 512)       { ap = Ahi + 16 * 512; koff = k0; }
        else if (k0 < 1024) { ap = Alo;            koff = k0 - 512; }
        else                { ap = Ahi + 16 * 512; koff = k0 - 1024; }
        bs8 a[2], b[8];
        #pragma unroll
        for (int mf = 0; mf < 2; ++mf) {
            const int i = mf * 16 + lrow;
            const int j = (koff >> 3) + lkb;
            a[mf] = *(const bs8*)(ap + i * 512 + (j ^ (i & 7)) * 8);
        }
        #pragma unroll
        for (int nf = 0; nf < 8; ++nf) {
            const int nr = wid * 128 + nf * 16 + lrow;
            b[nf] = *(const bs8*)(bb + nr * 32 + (lkb ^ fsw2(nr)) * 8);
        }
        #pragma unroll
        for (int mf = 0; mf < 2; ++mf)
            #pragma unroll
            for (int nf = 0; nf < 8; ++nf)
                yacc[mf][nf] = __builtin_amdgcn_mfma_f32_16x16x32_bf16(
                    a[mf], b[nf], yacc[mf][nf], 0, 0, 0);
    };
    auto kbOf = [](int k) { return (k < 512) ? k : k - 512; };  // Ghi,Ghi,Glo

    stageB(Bb0, 0, 0);
    __syncthreads();
    for (int k0 = 0; k0 < 1536; k0 += 64) {
        stageB(Bb1, 0, kbOf(k0 + 32));
        computeY(Bb0, k0);
        __syncthreads();
        if (k0 + 64 < 1536) stageB(Bb0, 0, kbOf(k0 + 64));
        computeY(Bb1, k0 + 32);
        __syncthreads();
    }
    // Y epilogue -> LDS f32 (B buffers dead)
    #pragma unroll
    for (int mf = 0; mf < 2; ++mf)
        #pragma unroll
        for (int nf = 0; nf < 8; ++nf)
            #pragma unroll
            for (int r = 0; r < 4; ++r) {
                const int row = mf * 16 + lkb * 4 + r;
                const int col = wid * 128 + nf * 16 + lrow;
                YL[row * 512 + col] = yacc[mf][nf][r];
            }
    __syncthreads();

    // ---- phase 3: attention, 8 tokens per wave ----
    for (int j8 = 0; j8 < 8; ++j8) {
        const int tloc = wid * 8 + j8;       // 0..31
        const int tg = r0 + tloc;
        const int tt = tt0 + tloc;

        float q[8];
        {
            const float4* yp = (const float4*)(YL + tloc * 512 + ln * 8);
            const float4 a = yp[0], c = yp[1];
            q[0] = a.x; q[1] = a.y; q[2] = a.z; q[3] = a.w;
            q[4] = c.x; q[5] = c.y; q[6] = c.z; q[7] = c.w;
        }

        float lw[16];
        #pragma unroll
        for (int w = 0; w < WIN; ++w) {
            const int src = tt - (WIN - 1) + w;
            float dot = 0.0f;
            if (src >= 0) {
                const int sl = tloc + 1 + w;     // local A row 1..47
                float xv[8];
                if (sl >= 16) {                  // output-region rows: hi+lo in LDS
                    const int js = (ln ^ (sl & 7)) * 8;
                    const us8 h8 = *(const us8*)(Ahi + sl * 512 + js);
                    const us8 l8 = *(const us8*)(Alo + (sl - 16) * 512 + js);
                    #pragma unroll
                    for (int e = 0; e < 8; ++e) xv[e] = bf2f(h8[e]) + bf2f(l8[e]);
                } else {                         // halo rows: exact f32 global
                    const float4* xr = (const float4*)
                        (X + (size_t)(bat * Tn + src) * 512 + ln * 8);
                    const float4 a = xr[0], c = xr[1];
                    xv[0] = a.x; xv[1] = a.y; xv[2] = a.z; xv[3] = a.w;
                    xv[4] = c.x; xv[5] = c.y; xv[6] = c.z; xv[7] = c.w;
                }
                #pragma unroll
                for (int e = 0; e < 8; ++e) dot += q[e] * xv[e];
            }
            #pragma unroll
            for (int st = 32; st > 0; st >>= 1) dot += __shfl_xor(dot, st, 64);
            lw[w] = (src >= 0) ? dot : 0.0f;
        }

        float mx = lw[0];
        #pragma unroll
        for (int w = 1; w < WIN; ++w) mx = fmaxf(mx, lw[w]);
        float den = 0.0f;
        float sc[16];
        #pragma unroll
        for (int w = 0; w < WIN; ++w) { sc[w] = expf(lw[w] - mx); den += sc[w]; }
        const float inv = 1.0f / den;

        float acc[8] = {};
        #pragma unroll
        for (int w = 0; w < WIN; ++w) {
            const int src = tt - (WIN - 1) + w;
            if (src >= 0) {
                const float sw = sc[w] * inv;
                const us8 vv = *(const us8*)
                    (Vblk + ((size_t)blk * 48 + tloc + 1 + w) * 512 + ln * 8);
                #pragma unroll
                for (int e = 0; e < 8; ++e) acc[e] += sw * bf2f(vv[e]);
            }
        }

        // concat X-copy from hi+lo (err ~4e-5) + answer
        float xo[8];
        {
            const int sl = 16 + tloc;
            const int js = (ln ^ (sl & 7)) * 8;
            const us8 h8 = *(const us8*)(Ahi + sl * 512 + js);
            const us8 l8 = *(const us8*)(Alo + tloc * 512 + js);
            #pragma unroll
            for (int e = 0; e < 8; ++e) xo[e] = bf2f(h8[e]) + bf2f(l8[e]);
        }
        float* o0 = out + (size_t)tg * 1024 + ln * 8;
        *(float4*)o0       = make_float4(xo[0], xo[1], xo[2], xo[3]);
        *(float4*)(o0 + 4) = make_float4(xo[4], xo[5], xo[6], xo[7]);
        float* o1 = o0 + 512;
        *(float4*)o1       = make_float4(acc[0], acc[1], acc[2], acc[3]);
        *(float4*)(o1 + 4) = make_float4(acc[4], acc[5], acc[6], acc[7]);
    }
}

// ---------------------------------------------------------------------------
extern "C" void kernel_launch(void* const* d_in, const int* in_sizes, int n_in,
                              void* d_out, int out_size, void* d_ws, size_t ws_size,
                              hipStream_t stream)
{
    const float* X  = (const float*)d_in[0];
    const float* Mw = (const float*)d_in[1];
    const float* Cw = (const float*)d_in[2];
    const float* Vw = (const float*)d_in[3];
    float* out = (float*)d_out;

    // ws layout (~19 MB):
    short* Bt = (short*)d_ws;                                   // 1024*1024 bf16 = 2 MB
    float* Gp = (float*)(Bt + (size_t)1024 * 1024);             // 4*512*512 f32 = 4 MB
    unsigned short* Vblk = (unsigned short*)(Gp + (size_t)4 * 512 * 512); // 256*48*512 = 12.6 MB

    wprep<<<320, 256, 0, stream>>>(Mw, Cw, Vw, Gp, Bt);
    pack_g<<<128, 256, 0, stream>>>(Gp, Bt);
    fused<<<256, 256, 0, stream>>>(X, Bt, Vblk, out);
}

// Round 7
// 89.043 us; speedup vs baseline: 1.9399x; 1.9399x over previous
//
#include <hip/hip_runtime.h>
#include <math.h>

// Problem constants (B=8, T=1024, D=512, LEFT=16, RIGHT=0)
constexpr int Tn = 1024;
constexpr int Dn = 512;
constexpr int BT = 8192;
constexpr int WIN = 16;

typedef short bs8 __attribute__((ext_vector_type(8)));     // 8 bf16 (bit pattern)
typedef unsigned short us8 __attribute__((ext_vector_type(8)));
typedef float fx4 __attribute__((ext_vector_type(4)));

// bf16 helpers (self-contained, RNE)
__device__ inline unsigned short f2bf(float f) {
    unsigned int u = __float_as_uint(f);
    u += 0x7FFFu + ((u >> 16) & 1u);
    return (unsigned short)(u >> 16);
}
__device__ inline float bf2f(unsigned short h) {
    return __uint_as_float(((unsigned int)h) << 16);
}
// chunk-swizzle involution: spreads ds_read banks (bijective per 4-chunk row)
__device__ inline int fsw(int m) { return (m & 3) ^ ((m >> 2) & 3); }

// ---------------------------------------------------------------------------
// Kernel 1 (wprep): block-range dispatch
//   [0,2048):    split X (f32) -> Ap bf16 [8192][1024] = [hi|lo]
//   [2048,2560): split-K(8) partials of G = M @ C^T (K-chunk 64)
//   [2560,2624): split+transpose V (hi) -> Bt rows [512,1024)
// ---------------------------------------------------------------------------
__global__ __launch_bounds__(256) void wprep(
    const float* __restrict__ X,
    const float* __restrict__ Mw, const float* __restrict__ Cw,
    const float* __restrict__ Vw,
    short* __restrict__ Ap, float* __restrict__ Gp, short* __restrict__ Bt)
{
    __shared__ float smem[64 * 65];
    const int blk = blockIdx.x;
    const int tid = threadIdx.x;

    if (blk < 2048) {
        // ---- split_x ----
        const int i = blk * 256 + tid;
        const int m = i >> 6;
        const int kc = (i & 63) * 8;
        const float4* xp = (const float4*)(X + (size_t)m * Dn + kc);
        const float4 x0 = xp[0], x1 = xp[1];
        const float xs[8] = {x0.x, x0.y, x0.z, x0.w, x1.x, x1.y, x1.z, x1.w};
        union { bs8 v; unsigned short u[8]; } hi, lo;
        #pragma unroll
        for (int j = 0; j < 8; ++j) {
            const float x = xs[j];
            const unsigned short h = f2bf(x);
            hi.u[j] = h;
            lo.u[j] = f2bf(x - bf2f(h));
        }
        short* base = Ap + (size_t)m * 1024 + kc;
        *(bs8*)base         = hi.v;
        *(bs8*)(base + 512) = lo.v;
    } else if (blk < 2560) {
        // ---- g_partial: Gp[kc][b][a] = sum_{j in 64-chunk} M[a,j] C[b,j] ----
        float* As = smem;              // [64][17]
        float* Bs = smem + 64 * 17;
        const int bz = blk - 2048;
        const int kch = bz >> 6;            // 0..7
        const int r6 = bz & 63;
        const int b0 = (r6 & 7) * 64;
        const int a0 = (r6 >> 3) * 64;
        const int tx = tid & 15, ty = tid >> 4;

        float acc[4][4] = {};
        for (int j0 = kch * 64; j0 < kch * 64 + 64; j0 += 16) {
            const int r = tid >> 2;
            const int c = (tid & 3) * 4;
            const float4 a = *(const float4*)(Mw + (size_t)(a0 + r) * Dn + j0 + c);
            As[r * 17 + c + 0] = a.x; As[r * 17 + c + 1] = a.y;
            As[r * 17 + c + 2] = a.z; As[r * 17 + c + 3] = a.w;
            const float4 b = *(const float4*)(Cw + (size_t)(b0 + r) * Dn + j0 + c);
            Bs[r * 17 + c + 0] = b.x; Bs[r * 17 + c + 1] = b.y;
            Bs[r * 17 + c + 2] = b.z; Bs[r * 17 + c + 3] = b.w;
            __syncthreads();
            #pragma unroll
            for (int kk = 0; kk < 16; ++kk) {
                float av[4], bv[4];
                #pragma unroll
                for (int i = 0; i < 4; ++i) av[i] = As[(ty * 4 + i) * 17 + kk];
                #pragma unroll
                for (int j = 0; j < 4; ++j) bv[j] = Bs[(tx * 4 + j) * 17 + kk];
                #pragma unroll
                for (int i = 0; i < 4; ++i)
                    #pragma unroll
                    for (int j = 0; j < 4; ++j)
                        acc[i][j] += av[i] * bv[j];
            }
            __syncthreads();
        }
        #pragma unroll
        for (int j = 0; j < 4; ++j) {
            const int b = b0 + tx * 4 + j;
            float4 col = make_float4(acc[0][j], acc[1][j], acc[2][j], acc[3][j]);
            *(float4*)(Gp + ((size_t)kch * 512 + b) * 512 + a0 + ty * 4) = col;
        }
    } else {
        // ---- split_v: Bt[512+n][k] = hi(V[k][n]) ----
        float* tile = smem;            // [64][65]
        const int z = blk - 2560;
        const int k0 = (z & 7) * 64;
        const int n0 = (z >> 3) * 64;
        #pragma unroll
        for (int rr = 0; rr < 4; ++rr) {
            const int row = (tid >> 4) * 4 + rr;
            const int col = (tid & 15) * 4;
            const float4 w = *(const float4*)(Vw + (size_t)(k0 + row) * Dn + n0 + col);
            tile[row * 65 + col + 0] = w.x; tile[row * 65 + col + 1] = w.y;
            tile[row * 65 + col + 2] = w.z; tile[row * 65 + col + 3] = w.w;
        }
        __syncthreads();
        const int n  = tid >> 2;
        const int ks = (tid & 3) * 16;
        union { bs8 v; unsigned short u[8]; } hi0, hi1;
        #pragma unroll
        for (int i = 0; i < 8; ++i) {
            hi0.u[i] = f2bf(tile[(ks + i) * 65 + n]);
            hi1.u[i] = f2bf(tile[(ks + 8 + i) * 65 + n]);
        }
        short* base = Bt + (size_t)(512 + n0 + n) * 1024 + k0 + ks;
        *(bs8*)base       = hi0.v;
        *(bs8*)(base + 8) = hi1.v;
    }
}

// ---------------------------------------------------------------------------
// Kernel 2: pack G = sum of 8 partials, split hi/lo into Bt rows [0,512):
// Bt[b][a] = hi(G[a][b]), Bt[b][512+a] = lo.
// ---------------------------------------------------------------------------
__global__ __launch_bounds__(256) void pack_g(const float* __restrict__ Gp,
                                              short* __restrict__ Bt)
{
    const int i = blockIdx.x * 256 + threadIdx.x;   // 32768 threads
    const int b = i >> 6;
    const int a8 = (i & 63) * 8;
    float s[8] = {};
    #pragma unroll
    for (int kc = 0; kc < 8; ++kc) {
        const float* p = Gp + ((size_t)kc * 512 + b) * 512 + a8;
        const float4 p0 = *(const float4*)p;
        const float4 p1 = *(const float4*)(p + 4);
        s[0] += p0.x; s[1] += p0.y; s[2] += p0.z; s[3] += p0.w;
        s[4] += p1.x; s[5] += p1.y; s[6] += p1.z; s[7] += p1.w;
    }
    union { bs8 v; unsigned short u[8]; } hi, lo;
    #pragma unroll
    for (int j = 0; j < 8; ++j) {
        const unsigned short h = f2bf(s[j]);
        hi.u[j] = h;
        lo.u[j] = f2bf(s[j] - bf2f(h));
    }
    short* base = Bt + (size_t)b * 1024 + a8;
    *(bs8*)base         = hi.v;
    *(bs8*)(base + 512) = lo.v;
}

// ---------------------------------------------------------------------------
// Kernel 3: bf16 MFMA GEMM, 512 threads (8 waves), double-buffered.
//   Y = X@G (K'=1536 = AhiGhi + AloGhi + AhiGlo) -> f32 to out[...,512:1024]
//   V' = X@V hi (K'=512) -> Vws bf16
// 128x128 tile, BK=32; 8 waves as 2(wr) x 4(wc), each 64x32 (acc[4][2]).
// Grid 512: 256 Y-blocks dispatched first, 256 V-blocks backfill ->
// each CU gets 1 long + 1 short block (uniform 64 K-steps), 16 waves/CU.
// ---------------------------------------------------------------------------
__global__ __launch_bounds__(512) void gemm_mfma(
    const short* __restrict__ Ap, const short* __restrict__ Bt,
    float* __restrict__ outY, unsigned short* __restrict__ Vws)
{
    __shared__ short Asl[2][128 * 32];   // 2 x 8 KB
    __shared__ short Bsl[2][128 * 32];

    const int lin = blockIdx.x;              // 0..511
    const int xcd = lin & 7;
    const int s   = lin >> 3;                // 0..63
    int mt, nt;
    if (s < 32) {                            // Y blocks (long K) first
        mt = xcd * 8 + (s & 7);
        nt = s >> 3;                         // 0..3
    } else {                                 // V blocks
        const int v = s - 32;
        mt = xcd * 8 + (v & 7);
        nt = 4 + (v >> 3);                   // 4..7
    }
    const int m0 = mt * 128, n0g = nt * 128;
    const int slab = nt >> 2;                // 0=Y, 1=V
    const int kEnd = slab ? 512 : 1536;

    const int tid = threadIdx.x;
    const int ln  = tid & 63;
    const int wid = tid >> 6;                // 0..7
    const int wr = wid >> 2, wc = wid & 3;   // 2 x 4 waves
    const int lrow = ln & 15;
    const int lkb  = ln >> 4;                // 0..3

    fx4 acc[4][2] = {};

    const int am = tid >> 2;                       // 0..127
    const int aj = (tid & 3) ^ fsw(am);            // chunk actually staged
    const size_t abase = (size_t)(m0  + am) * 1024 + aj * 8;
    const size_t bbase = (size_t)(n0g + am) * 1024 + aj * 8;

    auto stage = [&](int bi, int k0s) {
        const int ka0 = (k0s < 1024) ? k0s : (k0s - 1024);   // A: hi,lo,hi
        const int kb0 = (k0s < 512)  ? k0s : (k0s - 512);    // B: hi,hi,lo
        __builtin_amdgcn_global_load_lds(
            (const __attribute__((address_space(1))) unsigned int*)(Ap + abase + ka0),
            (__attribute__((address_space(3))) unsigned int*)(&Asl[bi][tid * 8]), 16, 0, 0);
        __builtin_amdgcn_global_load_lds(
            (const __attribute__((address_space(1))) unsigned int*)(Bt + bbase + kb0),
            (__attribute__((address_space(3))) unsigned int*)(&Bsl[bi][tid * 8]), 16, 0, 0);
    };

    auto compute = [&](const short* As_, const short* Bs_) {
        bs8 a[4], b[2];
        #pragma unroll
        for (int mf = 0; mf < 4; ++mf) {
            const int m = wr * 64 + mf * 16 + lrow;
            a[mf] = *(const bs8*)(As_ + (m * 4 + (lkb ^ fsw(m))) * 8);
        }
        #pragma unroll
        for (int nf = 0; nf < 2; ++nf) {
            const int n = wc * 32 + nf * 16 + lrow;
            b[nf] = *(const bs8*)(Bs_ + (n * 4 + (lkb ^ fsw(n))) * 8);
        }
        #pragma unroll
        for (int mf = 0; mf < 4; ++mf)
            #pragma unroll
            for (int nf = 0; nf < 2; ++nf)
                acc[mf][nf] = __builtin_amdgcn_mfma_f32_16x16x32_bf16(
                    a[mf], b[nf], acc[mf][nf], 0, 0, 0);
    };

    stage(0, 0);
    __syncthreads();
    for (int k0 = 0; k0 < kEnd; k0 += 64) {
        stage(1, k0 + 32);                 // kEnd is a multiple of 64
        compute(Asl[0], Bsl[0]);
        __syncthreads();
        if (k0 + 64 < kEnd) stage(0, k0 + 64);
        compute(Asl[1], Bsl[1]);
        __syncthreads();
    }

    #pragma unroll
    for (int mf = 0; mf < 4; ++mf) {
        #pragma unroll
        for (int nf = 0; nf < 2; ++nf) {
            const int col = n0g + wc * 32 + nf * 16 + lrow;   // absolute n'
            #pragma unroll
            for (int r = 0; r < 4; ++r) {
                const int row = m0 + wr * 64 + mf * 16 + lkb * 4 + r;
                const float v = acc[mf][nf][r];
                if (slab == 0) outY[(size_t)row * 1024 + 512 + col] = v;
                else           Vws[(size_t)row * 512 + (col - 512)] = f2bf(v);
            }
        }
    }
}

// ---------------------------------------------------------------------------
// Kernel 4: windowed attention. One wave per token, XCD-swizzled block ids.
//   logit[t,s] = Y[t] . X[s]  (Y from d_out scratch, X exact f32)
//   Invalid slots (src<0): logit = 0 exactly, no V term.
// ---------------------------------------------------------------------------
__global__ __launch_bounds__(256) void attn_win(
    const float* __restrict__ X,
    const unsigned short* __restrict__ Vws,
    float* __restrict__ out)
{
    const int lin = blockIdx.x;                       // 0..2047
    const int swz = (lin & 7) * 256 + (lin >> 3);     // 8 XCDs x 256 blocks
    const int wid = threadIdx.x >> 6;
    const int ln  = threadIdx.x & 63;
    const int tg  = swz * 4 + wid;
    const int b   = tg >> 10;
    const int tt  = tg & 1023;

    // Y fragment from d_out[..., 512:1024]
    float q[8];
    {
        const float4* qp = (const float4*)(out + (size_t)tg * 1024 + 512);
        const float4 a = qp[ln * 2];
        const float4 c = qp[ln * 2 + 1];
        q[0] = a.x; q[1] = a.y; q[2] = a.z; q[3] = a.w;
        q[4] = c.x; q[5] = c.y; q[6] = c.z; q[7] = c.w;
    }

    float lw[16];
    float4 x15a, x15b;   // own X row, saved from w=15 for the concat copy
    #pragma unroll
    for (int w = 0; w < WIN; ++w) {
        const int src = tt - (WIN - 1) + w;
        float dot = 0.0f;
        if (src >= 0) {
            const float* xrow = X + (size_t)(b * Tn + src) * Dn + ln * 8;
            const float4 k0 = *(const float4*)xrow;
            const float4 k1 = *(const float4*)(xrow + 4);
            dot = q[0] * k0.x + q[1] * k0.y + q[2] * k0.z + q[3] * k0.w
                + q[4] * k1.x + q[5] * k1.y + q[6] * k1.z + q[7] * k1.w;
            if (w == WIN - 1) { x15a = k0; x15b = k1; }
        }
        #pragma unroll
        for (int st = 32; st > 0; st >>= 1) dot += __shfl_xor(dot, st, 64);
        lw[w] = (src >= 0) ? dot : 0.0f;
    }

    // Concat copy: out[..., 0:512] = X row (reuses the w=15 load)
    {
        float* o0 = out + (size_t)tg * 1024 + ln * 8;
        *(float4*)o0       = x15a;
        *(float4*)(o0 + 4) = x15b;
    }

    float mx = lw[0];
    #pragma unroll
    for (int w = 1; w < WIN; ++w) mx = fmaxf(mx, lw[w]);
    float den = 0.0f;
    float sc[16];
    #pragma unroll
    for (int w = 0; w < WIN; ++w) { sc[w] = expf(lw[w] - mx); den += sc[w]; }
    const float inv = 1.0f / den;

    float acc[8] = {};
    #pragma unroll
    for (int w = 0; w < WIN; ++w) {
        const int src = tt - (WIN - 1) + w;
        if (src >= 0) {
            const float sw = sc[w] * inv;
            const us8 v = *(const us8*)(Vws + (size_t)(b * Tn + src) * Dn + ln * 8);
            #pragma unroll
            for (int j = 0; j < 8; ++j) acc[j] += sw * bf2f(v[j]);
        }
    }

    float* o1 = out + (size_t)tg * 1024 + 512 + ln * 8;
    *(float4*)o1       = make_float4(acc[0], acc[1], acc[2], acc[3]);
    *(float4*)(o1 + 4) = make_float4(acc[4], acc[5], acc[6], acc[7]);
}

// ---------------------------------------------------------------------------
extern "C" void kernel_launch(void* const* d_in, const int* in_sizes, int n_in,
                              void* d_out, int out_size, void* d_ws, size_t ws_size,
                              hipStream_t stream)
{
    const float* X  = (const float*)d_in[0];
    const float* Mw = (const float*)d_in[1];
    const float* Cw = (const float*)d_in[2];
    const float* Vw = (const float*)d_in[3];
    float* out = (float*)d_out;

    // ws layout (34 MB total):
    short* Ap = (short*)d_ws;                                          // 16 MB
    short* Bt = Ap + (size_t)BT * 1024;                                // 2 MB
    unsigned short* Vws = (unsigned short*)(Bt + (size_t)1024 * 1024); // 8 MB
    float* Gp = (float*)(Vws + (size_t)BT * Dn);                       // 8 MB

    wprep<<<2624, 256, 0, stream>>>(X, Mw, Cw, Vw, Ap, Gp, Bt);
    pack_g<<<128, 256, 0, stream>>>(Gp, Bt);
    gemm_mfma<<<512, 512, 0, stream>>>(Ap, Bt, out, Vws);
    attn_win<<<2048, 256, 0, stream>>>(X, Vws, out);
}

// Round 8
// 82.381 us; speedup vs baseline: 2.0968x; 1.0809x over previous
//
#include <hip/hip_runtime.h>
#include <math.h>

// Problem constants (B=8, T=1024, D=512, LEFT=16, RIGHT=0)
constexpr int Tn = 1024;
constexpr int Dn = 512;
constexpr int BT = 8192;
constexpr int WIN = 16;

typedef short bs8 __attribute__((ext_vector_type(8)));     // 8 bf16 (bit pattern)
typedef short sh4 __attribute__((ext_vector_type(4)));     // 4 bf16 (8 B)
typedef unsigned short us8 __attribute__((ext_vector_type(8)));
typedef float fx4 __attribute__((ext_vector_type(4)));

// bf16 helpers (self-contained, RNE)
__device__ inline unsigned short f2bf(float f) {
    unsigned int u = __float_as_uint(f);
    u += 0x7FFFu + ((u >> 16) & 1u);
    return (unsigned short)(u >> 16);
}
__device__ inline float bf2f(unsigned short h) {
    return __uint_as_float(((unsigned int)h) << 16);
}
// chunk-swizzle involution: spreads ds_read banks (bijective per 4-chunk row)
__device__ inline int fsw(int m) { return (m & 3) ^ ((m >> 2) & 3); }

// ---------------------------------------------------------------------------
// Kernel 1 (wprep): block-range dispatch
//   [0,2048):    split X -> Ap bf16 [8192][1024]=[hi|lo]  AND copy X->out[:,0:512]
//   [2048,2560): split-K(8) partials of G = M @ C^T (K-chunk 64)
//   [2560,2624): split+transpose V (hi) -> Bt rows [512,1024)
// ---------------------------------------------------------------------------
__global__ __launch_bounds__(256) void wprep(
    const float* __restrict__ X,
    const float* __restrict__ Mw, const float* __restrict__ Cw,
    const float* __restrict__ Vw,
    short* __restrict__ Ap, float* __restrict__ Gp, short* __restrict__ Bt,
    float* __restrict__ out)
{
    __shared__ float smem[64 * 65];
    const int blk = blockIdx.x;
    const int tid = threadIdx.x;

    if (blk < 2048) {
        // ---- split_x + concat copy ----
        const int i = blk * 256 + tid;
        const int m = i >> 6;
        const int kc = (i & 63) * 8;
        const float4* xp = (const float4*)(X + (size_t)m * Dn + kc);
        const float4 x0 = xp[0], x1 = xp[1];
        const float xs[8] = {x0.x, x0.y, x0.z, x0.w, x1.x, x1.y, x1.z, x1.w};
        union { bs8 v; unsigned short u[8]; } hi, lo;
        #pragma unroll
        for (int j = 0; j < 8; ++j) {
            const float x = xs[j];
            const unsigned short h = f2bf(x);
            hi.u[j] = h;
            lo.u[j] = f2bf(x - bf2f(h));
        }
        short* base = Ap + (size_t)m * 1024 + kc;
        *(bs8*)base         = hi.v;
        *(bs8*)(base + 512) = lo.v;
        // exact f32 concat copy
        float* o = out + (size_t)m * 1024 + kc;
        *(float4*)o       = x0;
        *(float4*)(o + 4) = x1;
    } else if (blk < 2560) {
        // ---- g_partial: Gp[kc][b][a] = sum_{j in 64-chunk} M[a,j] C[b,j] ----
        float* As = smem;              // [64][17]
        float* Bs = smem + 64 * 17;
        const int bz = blk - 2048;
        const int kch = bz >> 6;            // 0..7
        const int r6 = bz & 63;
        const int b0 = (r6 & 7) * 64;
        const int a0 = (r6 >> 3) * 64;
        const int tx = tid & 15, ty = tid >> 4;

        float acc[4][4] = {};
        for (int j0 = kch * 64; j0 < kch * 64 + 64; j0 += 16) {
            const int r = tid >> 2;
            const int c = (tid & 3) * 4;
            const float4 a = *(const float4*)(Mw + (size_t)(a0 + r) * Dn + j0 + c);
            As[r * 17 + c + 0] = a.x; As[r * 17 + c + 1] = a.y;
            As[r * 17 + c + 2] = a.z; As[r * 17 + c + 3] = a.w;
            const float4 b = *(const float4*)(Cw + (size_t)(b0 + r) * Dn + j0 + c);
            Bs[r * 17 + c + 0] = b.x; Bs[r * 17 + c + 1] = b.y;
            Bs[r * 17 + c + 2] = b.z; Bs[r * 17 + c + 3] = b.w;
            __syncthreads();
            #pragma unroll
            for (int kk = 0; kk < 16; ++kk) {
                float av[4], bv[4];
                #pragma unroll
                for (int i = 0; i < 4; ++i) av[i] = As[(ty * 4 + i) * 17 + kk];
                #pragma unroll
                for (int j = 0; j < 4; ++j) bv[j] = Bs[(tx * 4 + j) * 17 + kk];
                #pragma unroll
                for (int i = 0; i < 4; ++i)
                    #pragma unroll
                    for (int j = 0; j < 4; ++j)
                        acc[i][j] += av[i] * bv[j];
            }
            __syncthreads();
        }
        #pragma unroll
        for (int j = 0; j < 4; ++j) {
            const int b = b0 + tx * 4 + j;
            float4 col = make_float4(acc[0][j], acc[1][j], acc[2][j], acc[3][j]);
            *(float4*)(Gp + ((size_t)kch * 512 + b) * 512 + a0 + ty * 4) = col;
        }
    } else {
        // ---- split_v: Bt[512+n][k] = hi(V[k][n]) ----
        float* tile = smem;            // [64][65]
        const int z = blk - 2560;
        const int k0 = (z & 7) * 64;
        const int n0 = (z >> 3) * 64;
        #pragma unroll
        for (int rr = 0; rr < 4; ++rr) {
            const int row = (tid >> 4) * 4 + rr;
            const int col = (tid & 15) * 4;
            const float4 w = *(const float4*)(Vw + (size_t)(k0 + row) * Dn + n0 + col);
            tile[row * 65 + col + 0] = w.x; tile[row * 65 + col + 1] = w.y;
            tile[row * 65 + col + 2] = w.z; tile[row * 65 + col + 3] = w.w;
        }
        __syncthreads();
        const int n  = tid >> 2;
        const int ks = (tid & 3) * 16;
        union { bs8 v; unsigned short u[8]; } hi0, hi1;
        #pragma unroll
        for (int i = 0; i < 8; ++i) {
            hi0.u[i] = f2bf(tile[(ks + i) * 65 + n]);
            hi1.u[i] = f2bf(tile[(ks + 8 + i) * 65 + n]);
        }
        short* base = Bt + (size_t)(512 + n0 + n) * 1024 + k0 + ks;
        *(bs8*)base       = hi0.v;
        *(bs8*)(base + 8) = hi1.v;
    }
}

// ---------------------------------------------------------------------------
// Kernel 2: pack G = sum of 8 partials, split hi/lo into Bt rows [0,512):
// Bt[b][a] = hi(G[a][b]), Bt[b][512+a] = lo.
// ---------------------------------------------------------------------------
__global__ __launch_bounds__(256) void pack_g(const float* __restrict__ Gp,
                                              short* __restrict__ Bt)
{
    const int i = blockIdx.x * 256 + threadIdx.x;   // 32768 threads
    const int b = i >> 6;
    const int a8 = (i & 63) * 8;
    float s[8] = {};
    #pragma unroll
    for (int kc = 0; kc < 8; ++kc) {
        const float* p = Gp + ((size_t)kc * 512 + b) * 512 + a8;
        const float4 p0 = *(const float4*)p;
        const float4 p1 = *(const float4*)(p + 4);
        s[0] += p0.x; s[1] += p0.y; s[2] += p0.z; s[3] += p0.w;
        s[4] += p1.x; s[5] += p1.y; s[6] += p1.z; s[7] += p1.w;
    }
    union { bs8 v; unsigned short u[8]; } hi, lo;
    #pragma unroll
    for (int j = 0; j < 8; ++j) {
        const unsigned short h = f2bf(s[j]);
        hi.u[j] = h;
        lo.u[j] = f2bf(s[j] - bf2f(h));
    }
    short* base = Bt + (size_t)b * 1024 + a8;
    *(bs8*)base         = hi.v;
    *(bs8*)(base + 512) = lo.v;
}

// ---------------------------------------------------------------------------
// Kernel 3: bf16 MFMA GEMM, 512 threads (8 waves), double-buffered.
//   Y = X@G (K'=1536 = AhiGhi + AloGhi + AhiGlo) -> Yh/Yl bf16 planes
//   V' = X@V hi (K'=512) -> Vt TRANSPOSED bf16 [512 d][8192 tok]
// 128x128 tile, BK=32; 8 waves as 2(wr) x 4(wc), each 64x32 (acc[4][2]).
// Grid 512: 256 Y-blocks dispatched first, 256 V-blocks backfill.
// ---------------------------------------------------------------------------
__global__ __launch_bounds__(512) void gemm_mfma(
    const short* __restrict__ Ap, const short* __restrict__ Bt,
    short* __restrict__ Yh, short* __restrict__ Yl, short* __restrict__ Vt)
{
    __shared__ short Asl[2][128 * 32];   // 2 x 8 KB
    __shared__ short Bsl[2][128 * 32];

    const int lin = blockIdx.x;              // 0..511
    const int xcd = lin & 7;
    const int s   = lin >> 3;                // 0..63
    int mt, nt;
    if (s < 32) {                            // Y blocks (long K) first
        mt = xcd * 8 + (s & 7);
        nt = s >> 3;                         // 0..3
    } else {                                 // V blocks
        const int v = s - 32;
        mt = xcd * 8 + (v & 7);
        nt = 4 + (v >> 3);                   // 4..7
    }
    const int m0 = mt * 128, n0g = nt * 128;
    const int slab = nt >> 2;                // 0=Y, 1=V
    const int kEnd = slab ? 512 : 1536;

    const int tid = threadIdx.x;
    const int ln  = tid & 63;
    const int wid = tid >> 6;                // 0..7
    const int wr = wid >> 2, wc = wid & 3;   // 2 x 4 waves
    const int lrow = ln & 15;
    const int lkb  = ln >> 4;                // 0..3

    fx4 acc[4][2] = {};

    const int am = tid >> 2;                       // 0..127
    const int aj = (tid & 3) ^ fsw(am);            // chunk actually staged
    const size_t abase = (size_t)(m0  + am) * 1024 + aj * 8;
    const size_t bbase = (size_t)(n0g + am) * 1024 + aj * 8;

    auto stage = [&](int bi, int k0s) {
        const int ka0 = (k0s < 1024) ? k0s : (k0s - 1024);   // A: hi,lo,hi
        const int kb0 = (k0s < 512)  ? k0s : (k0s - 512);    // B: hi,hi,lo
        __builtin_amdgcn_global_load_lds(
            (const __attribute__((address_space(1))) unsigned int*)(Ap + abase + ka0),
            (__attribute__((address_space(3))) unsigned int*)(&Asl[bi][tid * 8]), 16, 0, 0);
        __builtin_amdgcn_global_load_lds(
            (const __attribute__((address_space(1))) unsigned int*)(Bt + bbase + kb0),
            (__attribute__((address_space(3))) unsigned int*)(&Bsl[bi][tid * 8]), 16, 0, 0);
    };

    auto compute = [&](const short* As_, const short* Bs_) {
        bs8 a[4], b[2];
        #pragma unroll
        for (int mf = 0; mf < 4; ++mf) {
            const int m = wr * 64 + mf * 16 + lrow;
            a[mf] = *(const bs8*)(As_ + (m * 4 + (lkb ^ fsw(m))) * 8);
        }
        #pragma unroll
        for (int nf = 0; nf < 2; ++nf) {
            const int n = wc * 32 + nf * 16 + lrow;
            b[nf] = *(const bs8*)(Bs_ + (n * 4 + (lkb ^ fsw(n))) * 8);
        }
        #pragma unroll
        for (int mf = 0; mf < 4; ++mf)
            #pragma unroll
            for (int nf = 0; nf < 2; ++nf)
                acc[mf][nf] = __builtin_amdgcn_mfma_f32_16x16x32_bf16(
                    a[mf], b[nf], acc[mf][nf], 0, 0, 0);
    };

    stage(0, 0);
    __syncthreads();
    for (int k0 = 0; k0 < kEnd; k0 += 64) {
        stage(1, k0 + 32);                 // kEnd is a multiple of 64
        compute(Asl[0], Bsl[0]);
        __syncthreads();
        if (k0 + 64 < kEnd) stage(0, k0 + 64);
        compute(Asl[1], Bsl[1]);
        __syncthreads();
    }

    if (slab == 0) {
        // Y epilogue: split into Yh/Yl bf16 planes
        #pragma unroll
        for (int mf = 0; mf < 4; ++mf) {
            #pragma unroll
            for (int nf = 0; nf < 2; ++nf) {
                const int col = n0g + wc * 32 + nf * 16 + lrow;
                #pragma unroll
                for (int r = 0; r < 4; ++r) {
                    const int row = m0 + wr * 64 + mf * 16 + lkb * 4 + r;
                    const float v = acc[mf][nf][r];
                    const unsigned short h = f2bf(v);
                    Yh[(size_t)row * 512 + col] = (short)h;
                    Yl[(size_t)row * 512 + col] = (short)f2bf(v - bf2f(h));
                }
            }
        }
    } else {
        // V epilogue: transposed store Vt[d][token], 4 rows -> one 8B store
        #pragma unroll
        for (int mf = 0; mf < 4; ++mf) {
            #pragma unroll
            for (int nf = 0; nf < 2; ++nf) {
                const int c = (n0g - 512) + wc * 32 + nf * 16 + lrow;   // d
                const int row0 = m0 + wr * 64 + mf * 16 + lkb * 4;
                sh4 v4;
                #pragma unroll
                for (int r = 0; r < 4; ++r) v4[r] = (short)f2bf(acc[mf][nf][r]);
                *(sh4*)(Vt + (size_t)c * 8192 + row0) = v4;
            }
        }
    }
}

// ---------------------------------------------------------------------------
// Kernel 4: banded attention via MFMA. One wave per 16-token strip.
//   S[i][j] = Y[t0+i] . X[t0-15+j]  (j=0..30 used, j=31 pad), computed as
//   YhiXhi + YloXhi + YhiXlo with 16x16x32 MFMA (2 N-tiles, K=512).
//   Band: token i uses j in [i, i+15]; src<0 slots contribute exp(0) to the
//   denominator and 0 to the numerator (reference semantics).
//   P(16x32) bf16 -> transpose via 1KB LDS -> answer = P @ V'_window via
//   32 MFMA, B loaded contiguously from transposed Vt[d][token].
// ---------------------------------------------------------------------------
__global__ __launch_bounds__(64) void attn_mfma(
    const short* __restrict__ Ap,
    const short* __restrict__ Yh, const short* __restrict__ Yl,
    const short* __restrict__ Vt, float* __restrict__ out)
{
    __shared__ short Plds[16 * 32];

    const int lin = blockIdx.x;                   // 0..511
    const int strip = (lin & 7) * 64 + (lin >> 3);  // XCD swizzle (512=8x64)
    const int t0 = strip * 16;
    const int bat = t0 >> 10;
    const int tt0 = t0 & 1023;
    const int l  = threadIdx.x;                   // 0..63
    const int lr = l & 15;
    const int lg = l >> 4;                        // 0..3

    // ---- S = Y . X^T (3-term split), 2 N-tiles ----
    const size_t yrow = (size_t)(t0 + lr) * 512 + lg * 8;
    const int srcl0 = tt0 - 15 + lr;              // local src for j=lr
    const int srcl1 = tt0 + 1 + lr;               // local src for j=lr+16
    const int r0c = srcl0 < 0 ? 0 : srcl0;
    const int r1c = srcl1 > 1023 ? 1023 : srcl1;  // only j=31 (masked) hits 1024
    const size_t xrow0 = ((size_t)(bat * 1024 + r0c)) * 1024 + lg * 8;
    const size_t xrow1 = ((size_t)(bat * 1024 + r1c)) * 1024 + lg * 8;

    fx4 s0a = {0,0,0,0}, s0b = {0,0,0,0};
    fx4 s1a = {0,0,0,0}, s1b = {0,0,0,0};
    #pragma unroll
    for (int k0 = 0; k0 < 512; k0 += 32) {
        const bs8 ah  = *(const bs8*)(Yh + yrow + k0);
        const bs8 al  = *(const bs8*)(Yl + yrow + k0);
        const bs8 bh0 = *(const bs8*)(Ap + xrow0 + k0);
        const bs8 bl0 = *(const bs8*)(Ap + xrow0 + 512 + k0);
        const bs8 bh1 = *(const bs8*)(Ap + xrow1 + k0);
        const bs8 bl1 = *(const bs8*)(Ap + xrow1 + 512 + k0);
        s0a = __builtin_amdgcn_mfma_f32_16x16x32_bf16(ah, bh0, s0a, 0, 0, 0);
        s0b = __builtin_amdgcn_mfma_f32_16x16x32_bf16(al, bh0, s0b, 0, 0, 0);
        s0b = __builtin_amdgcn_mfma_f32_16x16x32_bf16(ah, bl0, s0b, 0, 0, 0);
        s1a = __builtin_amdgcn_mfma_f32_16x16x32_bf16(ah, bh1, s1a, 0, 0, 0);
        s1b = __builtin_amdgcn_mfma_f32_16x16x32_bf16(al, bh1, s1b, 0, 0, 0);
        s1b = __builtin_amdgcn_mfma_f32_16x16x32_bf16(ah, bl1, s1b, 0, 0, 0);
    }

    // ---- band mask + softmax (per lane: 4 rows x 2 cols) ----
    #pragma unroll
    for (int r = 0; r < 4; ++r) {
        const int i = lg * 4 + r;
        const int d0 = lr - i;            // w-offset for j=lr
        const int d1 = lr + 16 - i;       // w-offset for j=lr+16
        const bool in0 = (d0 >= 0) && (d0 <= 15);
        const bool in1 = (d1 >= 0) && (d1 <= 15);
        const bool z0 = srcl0 < 0;        // src<0 -> logit 0 exactly
        float v0 = z0 ? 0.0f : (s0a[r] + s0b[r]);
        float v1 = s1a[r] + s1b[r];
        v0 = in0 ? v0 : -3.0e38f;
        v1 = in1 ? v1 : -3.0e38f;
        float m = fmaxf(v0, v1);
        #pragma unroll
        for (int st = 1; st < 16; st <<= 1) m = fmaxf(m, __shfl_xor(m, st, 64));
        const float e0 = in0 ? __expf(v0 - m) : 0.0f;
        const float e1 = in1 ? __expf(v1 - m) : 0.0f;
        float den = e0 + e1;
        #pragma unroll
        for (int st = 1; st < 16; st <<= 1) den += __shfl_xor(den, st, 64);
        const float inv = 1.0f / den;
        const float p0 = (in0 && !z0) ? e0 * inv : 0.0f;
        const float p1 = in1 ? e1 * inv : 0.0f;
        Plds[i * 32 + lr]      = (short)f2bf(p0);
        Plds[i * 32 + lr + 16] = (short)f2bf(p1);
    }
    __syncthreads();

    // ---- PV: answer(16x512) = P(16x32) @ V'_window(32x512) ----
    const bs8 pa = *(const bs8*)(Plds + lr * 32 + lg * 8);
    // B fragment: lane holds V'[src = tt0-15+lg*8+e][d]; contiguous in Vt[d][tok].
    // Negative/overflow token indices only occur where P=0; bytes there are
    // finite bf16 (Vt is last in ws, preceded by Yl), so 0*garbage = 0.
    const long svt = (long)bat * 1024 + (tt0 - 15 + lg * 8);
    #pragma unroll
    for (int nf = 0; nf < 32; ++nf) {
        const int d = nf * 16 + lr;
        const bs8 bv = *(const bs8*)(Vt + (long)d * 8192 + svt);
        fx4 c = {0, 0, 0, 0};
        c = __builtin_amdgcn_mfma_f32_16x16x32_bf16(pa, bv, c, 0, 0, 0);
        #pragma unroll
        for (int r = 0; r < 4; ++r)
            out[(size_t)(t0 + lg * 4 + r) * 1024 + 512 + d] = c[r];
    }
}

// ---------------------------------------------------------------------------
extern "C" void kernel_launch(void* const* d_in, const int* in_sizes, int n_in,
                              void* d_out, int out_size, void* d_ws, size_t ws_size,
                              hipStream_t stream)
{
    const float* X  = (const float*)d_in[0];
    const float* Mw = (const float*)d_in[1];
    const float* Cw = (const float*)d_in[2];
    const float* Vw = (const float*)d_in[3];
    float* out = (float*)d_out;

    // ws layout (50 MB total), Vt LAST (its -15-token guard reads land in Yl):
    short* Ap = (short*)d_ws;                                   // 16 MB
    short* Bt = Ap + (size_t)BT * 1024;                         // 2 MB
    float* Gp = (float*)(Bt + (size_t)1024 * 1024);             // 8 MB
    short* Yh = (short*)(Gp + (size_t)8 * 512 * 512);           // 8 MB
    short* Yl = Yh + (size_t)BT * 512;                          // 8 MB
    short* Vt = Yl + (size_t)BT * 512;                          // 8 MB

    wprep<<<2624, 256, 0, stream>>>(X, Mw, Cw, Vw, Ap, Gp, Bt, out);
    pack_g<<<128, 256, 0, stream>>>(Gp, Bt);
    gemm_mfma<<<512, 512, 0, stream>>>(Ap, Bt, Yh, Yl, Vt);
    attn_mfma<<<512, 64, 0, stream>>>(Ap, Yh, Yl, Vt, out);
}

// Round 9
// 67.142 us; speedup vs baseline: 2.5727x; 1.2270x over previous
//
#include <hip/hip_runtime.h>
#include <math.h>

// Problem constants (B=8, T=1024, D=512, LEFT=16, RIGHT=0)
constexpr int Tn = 1024;
constexpr int Dn = 512;
constexpr int BT = 8192;
constexpr int WIN = 16;

typedef short bs8 __attribute__((ext_vector_type(8)));     // 8 bf16 (bit pattern)
typedef short sh4 __attribute__((ext_vector_type(4)));     // 4 bf16 (8 B)
typedef unsigned short us8 __attribute__((ext_vector_type(8)));
typedef float fx4 __attribute__((ext_vector_type(4)));

// bf16 helpers (self-contained, RNE)
__device__ inline unsigned short f2bf(float f) {
    unsigned int u = __float_as_uint(f);
    u += 0x7FFFu + ((u >> 16) & 1u);
    return (unsigned short)(u >> 16);
}
__device__ inline float bf2f(unsigned short h) {
    return __uint_as_float(((unsigned int)h) << 16);
}
// chunk-swizzle involution: spreads ds_read banks (bijective per 4-chunk row)
__device__ inline int fsw(int m) { return (m & 3) ^ ((m >> 2) & 3); }

// ---------------------------------------------------------------------------
// Kernel 1 (wprep):
//   [0,512):   split-K(8) partials of G = M @ C^T (K-chunk 64)
//   [512,576): split+transpose V (hi) -> Bt rows [512,1024)
// ---------------------------------------------------------------------------
__global__ __launch_bounds__(256) void wprep(
    const float* __restrict__ Mw, const float* __restrict__ Cw,
    const float* __restrict__ Vw,
    float* __restrict__ Gp, short* __restrict__ Bt)
{
    __shared__ float smem[64 * 65];
    const int blk = blockIdx.x;
    const int tid = threadIdx.x;

    if (blk < 512) {
        // ---- g_partial: Gp[kc][b][a] = sum_{j in 64-chunk} M[a,j] C[b,j] ----
        float* As = smem;              // [64][17]
        float* Bs = smem + 64 * 17;
        const int kch = blk >> 6;           // 0..7
        const int r6 = blk & 63;
        const int b0 = (r6 & 7) * 64;
        const int a0 = (r6 >> 3) * 64;
        const int tx = tid & 15, ty = tid >> 4;

        float acc[4][4] = {};
        for (int j0 = kch * 64; j0 < kch * 64 + 64; j0 += 16) {
            const int r = tid >> 2;
            const int c = (tid & 3) * 4;
            const float4 a = *(const float4*)(Mw + (size_t)(a0 + r) * Dn + j0 + c);
            As[r * 17 + c + 0] = a.x; As[r * 17 + c + 1] = a.y;
            As[r * 17 + c + 2] = a.z; As[r * 17 + c + 3] = a.w;
            const float4 b = *(const float4*)(Cw + (size_t)(b0 + r) * Dn + j0 + c);
            Bs[r * 17 + c + 0] = b.x; Bs[r * 17 + c + 1] = b.y;
            Bs[r * 17 + c + 2] = b.z; Bs[r * 17 + c + 3] = b.w;
            __syncthreads();
            #pragma unroll
            for (int kk = 0; kk < 16; ++kk) {
                float av[4], bv[4];
                #pragma unroll
                for (int i = 0; i < 4; ++i) av[i] = As[(ty * 4 + i) * 17 + kk];
                #pragma unroll
                for (int j = 0; j < 4; ++j) bv[j] = Bs[(tx * 4 + j) * 17 + kk];
                #pragma unroll
                for (int i = 0; i < 4; ++i)
                    #pragma unroll
                    for (int j = 0; j < 4; ++j)
                        acc[i][j] += av[i] * bv[j];
            }
            __syncthreads();
        }
        #pragma unroll
        for (int j = 0; j < 4; ++j) {
            const int b = b0 + tx * 4 + j;
            float4 col = make_float4(acc[0][j], acc[1][j], acc[2][j], acc[3][j]);
            *(float4*)(Gp + ((size_t)kch * 512 + b) * 512 + a0 + ty * 4) = col;
        }
    } else {
        // ---- split_v: Bt[512+n][k] = hi(V[k][n]) ----
        float* tile = smem;            // [64][65]
        const int z = blk - 512;
        const int k0 = (z & 7) * 64;
        const int n0 = (z >> 3) * 64;
        #pragma unroll
        for (int rr = 0; rr < 4; ++rr) {
            const int row = (tid >> 4) * 4 + rr;
            const int col = (tid & 15) * 4;
            const float4 w = *(const float4*)(Vw + (size_t)(k0 + row) * Dn + n0 + col);
            tile[row * 65 + col + 0] = w.x; tile[row * 65 + col + 1] = w.y;
            tile[row * 65 + col + 2] = w.z; tile[row * 65 + col + 3] = w.w;
        }
        __syncthreads();
        const int n  = tid >> 2;
        const int ks = (tid & 3) * 16;
        union { bs8 v; unsigned short u[8]; } hi0, hi1;
        #pragma unroll
        for (int i = 0; i < 8; ++i) {
            hi0.u[i] = f2bf(tile[(ks + i) * 65 + n]);
            hi1.u[i] = f2bf(tile[(ks + 8 + i) * 65 + n]);
        }
        short* base = Bt + (size_t)(512 + n0 + n) * 1024 + k0 + ks;
        *(bs8*)base       = hi0.v;
        *(bs8*)(base + 8) = hi1.v;
    }
}

// ---------------------------------------------------------------------------
// Kernel 2: pack G = sum of 8 partials, split hi/lo into Bt rows [0,512):
// Bt[b][a] = hi(G[a][b]), Bt[b][512+a] = lo.
// ---------------------------------------------------------------------------
__global__ __launch_bounds__(256) void pack_g(const float* __restrict__ Gp,
                                              short* __restrict__ Bt)
{
    const int i = blockIdx.x * 256 + threadIdx.x;   // 32768 threads
    const int b = i >> 6;
    const int a8 = (i & 63) * 8;
    float s[8] = {};
    #pragma unroll
    for (int kc = 0; kc < 8; ++kc) {
        const float* p = Gp + ((size_t)kc * 512 + b) * 512 + a8;
        const float4 p0 = *(const float4*)p;
        const float4 p1 = *(const float4*)(p + 4);
        s[0] += p0.x; s[1] += p0.y; s[2] += p0.z; s[3] += p0.w;
        s[4] += p1.x; s[5] += p1.y; s[6] += p1.z; s[7] += p1.w;
    }
    union { bs8 v; unsigned short u[8]; } hi, lo;
    #pragma unroll
    for (int j = 0; j < 8; ++j) {
        const unsigned short h = f2bf(s[j]);
        hi.u[j] = h;
        lo.u[j] = f2bf(s[j] - bf2f(h));
    }
    short* base = Bt + (size_t)b * 1024 + a8;
    *(bs8*)base         = hi.v;
    *(bs8*)(base + 512) = lo.v;
}

// ---------------------------------------------------------------------------
// Kernel 3: bf16 MFMA GEMM, reg-staged f32 A (no Ap materialization).
// Per 32-K chunk: load X f32 -> convert hi/lo in VGPR -> ds_write; B planes
// (Ghi+Glo for Y, Vhi for V) via global_load_lds; all 3 split terms computed
// per chunk (AhiGhi + AloGhi + AhiGlo) -> 16 iterations, 1 barrier each.
//   Y (blocks 0..255):  -> Yh/Yl bf16 planes
//   V (blocks 256..511): -> Vt TRANSPOSED bf16 [512 d][8192 tok]
// 128x128 tile; 8 waves as 2(wr) x 4(wc), each 64x32 (acc[4][2]).
// ---------------------------------------------------------------------------
__global__ __launch_bounds__(512, 4) void gemm_mfma(
    const float* __restrict__ X, const short* __restrict__ Bt,
    short* __restrict__ Yh, short* __restrict__ Yl, short* __restrict__ Vt)
{
    // [buf][plane]: 0=Ahi 1=Alo 2=B0(Ghi/Vhi) 3=B1(Glo); 8KB planes, 64KB total
    __shared__ short lds[2][4][128 * 32];

    const int lin = blockIdx.x;              // 0..511
    const int xcd = lin & 7;
    const int s   = lin >> 3;                // 0..63
    int mt, nt;
    if (s < 32) {                            // Y blocks first
        mt = xcd * 8 + (s & 7);
        nt = s >> 3;                         // 0..3
    } else {
        const int v = s - 32;
        mt = xcd * 8 + (v & 7);
        nt = 4 + (v >> 3);                   // 4..7
    }
    const int m0 = mt * 128, n0g = nt * 128;
    const int slab = nt >> 2;                // 0=Y, 1=V

    const int tid = threadIdx.x;
    const int ln  = tid & 63;
    const int wid = tid >> 6;                // 0..7
    const int wr = wid >> 2, wc = wid & 3;   // 2 x 4 waves
    const int lrow = ln & 15;
    const int lkb  = ln >> 4;                // 0..3

    fx4 acc[4][2] = {};

    // A staging geometry: thread -> (row, 8-elem chunk)
    const int ar = tid >> 2;                 // 0..127
    const int aj = tid & 3;                  // chunk 0..3
    const int aoff = ar * 32 + (aj ^ fsw(ar)) * 8;   // swizzled LDS offset
    const float* xrow = X + (size_t)(m0 + ar) * 512 + aj * 8;

    // B staging geometry (pre-swizzled global source, linear LDS dest)
    const int bnr = tid >> 2, bjj = tid & 3;
    const int bjs = bjj ^ fsw(bnr);
    const size_t bsrc = (size_t)(n0g + bnr) * 1024 + bjs * 8;

    auto stageB = [&](int bi, int k0) {
        __builtin_amdgcn_global_load_lds(
            (const __attribute__((address_space(1))) unsigned int*)(Bt + bsrc + k0),
            (__attribute__((address_space(3))) unsigned int*)(&lds[bi][2][tid * 8]), 16, 0, 0);
        if (slab == 0)
            __builtin_amdgcn_global_load_lds(
                (const __attribute__((address_space(1))) unsigned int*)(Bt + bsrc + 512 + k0),
                (__attribute__((address_space(3))) unsigned int*)(&lds[bi][3][tid * 8]), 16, 0, 0);
    };
    auto writeA = [&](int bi, const float4& f0, const float4& f1) {
        const float xs[8] = {f0.x, f0.y, f0.z, f0.w, f1.x, f1.y, f1.z, f1.w};
        union { bs8 v; unsigned short u[8]; } hi, lo;
        #pragma unroll
        for (int e = 0; e < 8; ++e) {
            const unsigned short h = f2bf(xs[e]);
            hi.u[e] = h;
            lo.u[e] = f2bf(xs[e] - bf2f(h));
        }
        *(bs8*)(&lds[bi][0][aoff]) = hi.v;
        if (slab == 0) *(bs8*)(&lds[bi][1][aoff]) = lo.v;
    };
    auto compute = [&](int bi) {
        bs8 ah[4], al[4], b0[2], b1[2];
        #pragma unroll
        for (int mf = 0; mf < 4; ++mf) {
            const int m = wr * 64 + mf * 16 + lrow;
            const int off = m * 32 + ((lkb ^ fsw(m)) * 8);
            ah[mf] = *(const bs8*)(&lds[bi][0][off]);
            if (slab == 0) al[mf] = *(const bs8*)(&lds[bi][1][off]);
        }
        #pragma unroll
        for (int nf = 0; nf < 2; ++nf) {
            const int n = wc * 32 + nf * 16 + lrow;
            const int off = n * 32 + ((lkb ^ fsw(n)) * 8);
            b0[nf] = *(const bs8*)(&lds[bi][2][off]);
            if (slab == 0) b1[nf] = *(const bs8*)(&lds[bi][3][off]);
        }
        #pragma unroll
        for (int mf = 0; mf < 4; ++mf)
            #pragma unroll
            for (int nf = 0; nf < 2; ++nf) {
                acc[mf][nf] = __builtin_amdgcn_mfma_f32_16x16x32_bf16(
                    ah[mf], b0[nf], acc[mf][nf], 0, 0, 0);
                if (slab == 0) {
                    acc[mf][nf] = __builtin_amdgcn_mfma_f32_16x16x32_bf16(
                        al[mf], b0[nf], acc[mf][nf], 0, 0, 0);
                    acc[mf][nf] = __builtin_amdgcn_mfma_f32_16x16x32_bf16(
                        ah[mf], b1[nf], acc[mf][nf], 0, 0, 0);
                }
            }
    };

    // prologue: chunk 0 into buf 0
    {
        const float4 f0 = *(const float4*)xrow;
        const float4 f1 = *(const float4*)(xrow + 4);
        stageB(0, 0);
        writeA(0, f0, f1);
    }
    __syncthreads();

    for (int it = 0; it < 16; ++it) {
        const int bi = it & 1;
        float4 n0, n1;
        if (it < 15) {
            const float* p = xrow + (it + 1) * 32;
            n0 = *(const float4*)p;
            n1 = *(const float4*)(p + 4);
            stageB(bi ^ 1, (it + 1) * 32);
        }
        compute(bi);
        if (it < 15) writeA(bi ^ 1, n0, n1);
        __syncthreads();
    }

    if (slab == 0) {
        // Y epilogue: split into Yh/Yl bf16 planes
        #pragma unroll
        for (int mf = 0; mf < 4; ++mf) {
            #pragma unroll
            for (int nf = 0; nf < 2; ++nf) {
                const int col = n0g + wc * 32 + nf * 16 + lrow;
                #pragma unroll
                for (int r = 0; r < 4; ++r) {
                    const int row = m0 + wr * 64 + mf * 16 + lkb * 4 + r;
                    const float v = acc[mf][nf][r];
                    const unsigned short h = f2bf(v);
                    Yh[(size_t)row * 512 + col] = (short)h;
                    Yl[(size_t)row * 512 + col] = (short)f2bf(v - bf2f(h));
                }
            }
        }
    } else {
        // V epilogue: transposed store Vt[d][token], 4 rows -> one 8B store
        #pragma unroll
        for (int mf = 0; mf < 4; ++mf) {
            #pragma unroll
            for (int nf = 0; nf < 2; ++nf) {
                const int c = (n0g - 512) + wc * 32 + nf * 16 + lrow;   // d
                const int row0 = m0 + wr * 64 + mf * 16 + lkb * 4;
                sh4 v4;
                #pragma unroll
                for (int r = 0; r < 4; ++r) v4[r] = (short)f2bf(acc[mf][nf][r]);
                *(sh4*)(Vt + (size_t)c * 8192 + row0) = v4;
            }
        }
    }
}

// ---------------------------------------------------------------------------
// Kernel 4: banded attention via MFMA. One wave per 16-token strip.
//   S[i][j] = Y[t0+i] . X[t0-15+j]; Y = Yh+Yl (bf16 planes), X split in-lane
//   from exact f32 (hi/lo, 2^-17). 3-term MFMA per N-tile. Also performs the
//   concat copy out[...,0:512] = X from the same f32 loads.
//   Band: src<0 slots -> logit 0 exactly (exp(0) in denominator), no V term.
//   PV: P(16x32) bf16 via LDS transpose -> 32 MFMA against transposed Vt.
// ---------------------------------------------------------------------------
__global__ __launch_bounds__(64) void attn_mfma(
    const float* __restrict__ X,
    const short* __restrict__ Yh, const short* __restrict__ Yl,
    const short* __restrict__ Vt, float* __restrict__ out)
{
    __shared__ short Plds[16 * 32];

    const int lin = blockIdx.x;                   // 0..511
    const int strip = (lin & 7) * 64 + (lin >> 3);  // XCD swizzle (512=8x64)
    const int t0 = strip * 16;
    const int bat = t0 >> 10;
    const int tt0 = t0 & 1023;
    const int l  = threadIdx.x;                   // 0..63
    const int lr = l & 15;
    const int lg = l >> 4;                        // 0..3

    const size_t yrow = (size_t)(t0 + lr) * 512 + lg * 8;
    const int srcl0 = tt0 - 15 + lr;              // local src for j=lr
    const int srcl1 = tt0 + 1 + lr;               // local src for j=lr+16
    const int r0c = srcl0 < 0 ? 0 : srcl0;
    const int r1c = srcl1 > 1023 ? 1023 : srcl1;  // only j=31 (masked) hits 1024
    const size_t xrow0 = ((size_t)(bat * 1024 + r0c)) * 512 + lg * 8;
    const size_t xrow1 = ((size_t)(bat * 1024 + r1c)) * 512 + lg * 8;

    fx4 s0a = {0,0,0,0}, s0b = {0,0,0,0};
    fx4 s1a = {0,0,0,0}, s1b = {0,0,0,0};
    #pragma unroll
    for (int k0 = 0; k0 < 512; k0 += 32) {
        const bs8 ah = *(const bs8*)(Yh + yrow + k0);
        const bs8 al = *(const bs8*)(Yl + yrow + k0);
        const float4 p0a = *(const float4*)(X + xrow0 + k0);
        const float4 p0b = *(const float4*)(X + xrow0 + k0 + 4);
        const float4 p1a = *(const float4*)(X + xrow1 + k0);
        const float4 p1b = *(const float4*)(X + xrow1 + k0 + 4);
        const float x0s[8] = {p0a.x,p0a.y,p0a.z,p0a.w,p0b.x,p0b.y,p0b.z,p0b.w};
        const float x1s[8] = {p1a.x,p1a.y,p1a.z,p1a.w,p1b.x,p1b.y,p1b.z,p1b.w};
        union { bs8 v; unsigned short u[8]; } bh0, bl0, bh1, bl1;
        #pragma unroll
        for (int e = 0; e < 8; ++e) {
            unsigned short h = f2bf(x0s[e]);
            bh0.u[e] = h; bl0.u[e] = f2bf(x0s[e] - bf2f(h));
            h = f2bf(x1s[e]);
            bh1.u[e] = h; bl1.u[e] = f2bf(x1s[e] - bf2f(h));
        }
        s0a = __builtin_amdgcn_mfma_f32_16x16x32_bf16(ah, bh0.v, s0a, 0, 0, 0);
        s0b = __builtin_amdgcn_mfma_f32_16x16x32_bf16(al, bh0.v, s0b, 0, 0, 0);
        s0b = __builtin_amdgcn_mfma_f32_16x16x32_bf16(ah, bl0.v, s0b, 0, 0, 0);
        s1a = __builtin_amdgcn_mfma_f32_16x16x32_bf16(ah, bh1.v, s1a, 0, 0, 0);
        s1b = __builtin_amdgcn_mfma_f32_16x16x32_bf16(al, bh1.v, s1b, 0, 0, 0);
        s1b = __builtin_amdgcn_mfma_f32_16x16x32_bf16(ah, bl1.v, s1b, 0, 0, 0);

        // concat copy: rows t0..t0+15 from the same loads (exact f32)
        if (lr == 15) {               // xrow0 == row t0
            float* o = out + (size_t)t0 * 1024 + k0 + lg * 8;
            *(float4*)o       = p0a;
            *(float4*)(o + 4) = p0b;
        } else {                      // xrow1 == row t0+1+lr  (lr<15)
            float* o = out + (size_t)(t0 + 1 + lr) * 1024 + k0 + lg * 8;
            *(float4*)o       = p1a;
            *(float4*)(o + 4) = p1b;
        }
    }

    // ---- band mask + softmax (per lane: 4 rows x 2 cols) ----
    #pragma unroll
    for (int r = 0; r < 4; ++r) {
        const int i = lg * 4 + r;
        const int d0 = lr - i;            // w-offset for j=lr
        const int d1 = lr + 16 - i;       // w-offset for j=lr+16
        const bool in0 = (d0 >= 0) && (d0 <= 15);
        const bool in1 = (d1 >= 0) && (d1 <= 15);
        const bool z0 = srcl0 < 0;        // src<0 -> logit 0 exactly
        float v0 = z0 ? 0.0f : (s0a[r] + s0b[r]);
        float v1 = s1a[r] + s1b[r];
        v0 = in0 ? v0 : -3.0e38f;
        v1 = in1 ? v1 : -3.0e38f;
        float m = fmaxf(v0, v1);
        #pragma unroll
        for (int st = 1; st < 16; st <<= 1) m = fmaxf(m, __shfl_xor(m, st, 64));
        const float e0 = in0 ? __expf(v0 - m) : 0.0f;
        const float e1 = in1 ? __expf(v1 - m) : 0.0f;
        float den = e0 + e1;
        #pragma unroll
        for (int st = 1; st < 16; st <<= 1) den += __shfl_xor(den, st, 64);
        const float inv = 1.0f / den;
        const float p0 = (in0 && !z0) ? e0 * inv : 0.0f;
        const float p1 = in1 ? e1 * inv : 0.0f;
        Plds[i * 32 + lr]      = (short)f2bf(p0);
        Plds[i * 32 + lr + 16] = (short)f2bf(p1);
    }
    __syncthreads();

    // ---- PV: answer(16x512) = P(16x32) @ V'_window(32x512) ----
    const bs8 pa = *(const bs8*)(Plds + lr * 32 + lg * 8);
    // OOB token indices only occur where P=0; neighboring ws bytes are finite
    // bf16 (Vt preceded by Yl), so 0*garbage = 0.
    const long svt = (long)bat * 1024 + (tt0 - 15 + lg * 8);
    #pragma unroll
    for (int nf = 0; nf < 32; ++nf) {
        const int d = nf * 16 + lr;
        const bs8 bv = *(const bs8*)(Vt + (long)d * 8192 + svt);
        fx4 c = {0, 0, 0, 0};
        c = __builtin_amdgcn_mfma_f32_16x16x32_bf16(pa, bv, c, 0, 0, 0);
        #pragma unroll
        for (int r = 0; r < 4; ++r)
            out[(size_t)(t0 + lg * 4 + r) * 1024 + 512 + d] = c[r];
    }
}

// ---------------------------------------------------------------------------
extern "C" void kernel_launch(void* const* d_in, const int* in_sizes, int n_in,
                              void* d_out, int out_size, void* d_ws, size_t ws_size,
                              hipStream_t stream)
{
    const float* X  = (const float*)d_in[0];
    const float* Mw = (const float*)d_in[1];
    const float* Cw = (const float*)d_in[2];
    const float* Vw = (const float*)d_in[3];
    float* out = (float*)d_out;

    // ws layout (34 MB total), Vt LAST (its -15-token guard reads land in Yl):
    short* Bt = (short*)d_ws;                                   // 2 MB
    float* Gp = (float*)(Bt + (size_t)1024 * 1024);             // 8 MB
    short* Yh = (short*)(Gp + (size_t)8 * 512 * 512);           // 8 MB
    short* Yl = Yh + (size_t)BT * 512;                          // 8 MB
    short* Vt = Yl + (size_t)BT * 512;                          // 8 MB

    wprep<<<576, 256, 0, stream>>>(Mw, Cw, Vw, Gp, Bt);
    pack_g<<<128, 256, 0, stream>>>(Gp, Bt);
    gemm_mfma<<<512, 512, 0, stream>>>(X, Bt, Yh, Yl, Vt);
    attn_mfma<<<512, 64, 0, stream>>>(X, Yh, Yl, Vt, out);
}